// Round 1
// baseline (5362.858 us; speedup 1.0000x reference)
//
#include <hip/hip_runtime.h>
#include <hip/hip_bf16.h>
#include <cstddef>
#include <cstdint>

#define TIC 16

// ---------------------------------------------------------------------------
// prep: transpose weights for coalesced access
//   wT1[k*256+oc]            = conv1_w[oc*81 + k]            (81*256)
//   wT2[((k*256)+ic)*256+ch] = prim_w[(ch*256+ic)*81 + k]    (81*256*256)
// grid*block == 81*256*256 exactly.
// ---------------------------------------------------------------------------
__global__ __launch_bounds__(256) void prep_kernel(
    const float* __restrict__ cw, const float* __restrict__ pw,
    float* __restrict__ wT1, float* __restrict__ wT2)
{
    int idx = blockIdx.x * 256 + threadIdx.x;
    if (idx < 81 * 256) {
        int k = idx >> 8, oc = idx & 255;
        wT1[idx] = cw[oc * 81 + k];
    }
    int ch = idx & 255;
    int t  = idx >> 8;
    int ic = t & 255;
    int k  = t >> 8;
    wT2[idx] = pw[((ch << 8) + ic) * 81 + k];
}

// ---------------------------------------------------------------------------
// conv1: [B,1,28,28] * [256,1,9,9] -> xc [bc][400][256]  (NHWC), +bias, ReLU
// one block per image, thread = out channel
// ---------------------------------------------------------------------------
__global__ __launch_bounds__(256) void conv1_kernel(
    const float* __restrict__ img,   // [B][784]
    const float* __restrict__ wT1,   // [81][256]
    const float* __restrict__ bias,  // [256]
    float* __restrict__ xc,          // [bc][400][256]
    int b0)
{
    const int bl = blockIdx.x;
    const int oc = threadIdx.x;
    __shared__ float im[784];
    const float* ib = img + (size_t)(b0 + bl) * 784;
    for (int e = oc; e < 784; e += 256) im[e] = ib[e];
    float w[81];
#pragma unroll
    for (int k = 0; k < 81; ++k) w[k] = wT1[k * 256 + oc];
    float bv = bias[oc];
    __syncthreads();
    float* ob = xc + (size_t)bl * 400 * 256 + oc;
    for (int oy = 0; oy < 20; ++oy) {
        for (int ox = 0; ox < 20; ++ox) {
            float a = bv;
#pragma unroll
            for (int ky = 0; ky < 9; ++ky)
#pragma unroll
                for (int kx = 0; kx < 9; ++kx)
                    a = fmaf(w[ky * 9 + kx], im[(oy + ky) * 28 + ox + kx], a);
            ob[(oy * 20 + ox) * 256] = fmaxf(a, 0.f);
        }
    }
}

// ---------------------------------------------------------------------------
// primary caps: xc [bc][400][256] * wT2 [81][256][256] stride2 -> prim[256][6][6]
// then +bias, regroup to nodes (n = (ch%32)*36 + s, d = ch/32), squash over d,
// write u [B][1152][8].  One block per image, thread = out channel, 36 acc.
// ---------------------------------------------------------------------------
__global__ __launch_bounds__(256) void primary_kernel(
    const float* __restrict__ xc,    // [bc][400][256]
    const float* __restrict__ wT2,   // [81][256][256] (k, ic, ch)
    const float* __restrict__ pb,    // [256]
    float* __restrict__ u,           // [B][1152][8]
    int b0)
{
    const int bl = blockIdx.x;
    const int ch = threadIdx.x;
    __shared__ float smem[9216];     // 36.9 KB: x-slice (6400) then prim[256][36]
    float acc[36];
#pragma unroll
    for (int s = 0; s < 36; ++s) acc[s] = 0.f;
    const float* xb = xc + (size_t)bl * 400 * 256;

    for (int ic0 = 0; ic0 < 256; ic0 += TIC) {
        __syncthreads();
        // stage x[., ., ic0:ic0+16] as [400][16] (float4 loads)
        for (int v = ch; v < 400 * TIC / 4; v += 256) {
            int p = v >> 2, q = v & 3;
            *(float4*)&smem[p * TIC + q * 4] =
                *(const float4*)&xb[p * 256 + ic0 + q * 4];
        }
        __syncthreads();
        for (int icl = 0; icl < TIC; ++icl) {
            int ic = ic0 + icl;
#pragma unroll
            for (int ky = 0; ky < 9; ++ky) {
                float wk[9];
#pragma unroll
                for (int kx = 0; kx < 9; ++kx)
                    wk[kx] = wT2[((ky * 9 + kx) * 256 + ic) * 256 + ch];
#pragma unroll
                for (int oy = 0; oy < 6; ++oy) {
                    const int y = 2 * oy + ky;
                    float xr[19];
#pragma unroll
                    for (int xx = 0; xx < 19; ++xx)
                        xr[xx] = smem[(y * 20 + xx) * TIC + icl];
#pragma unroll
                    for (int ox = 0; ox < 6; ++ox)
#pragma unroll
                        for (int kx = 0; kx < 9; ++kx)
                            acc[oy * 6 + ox] =
                                fmaf(wk[kx], xr[2 * ox + kx], acc[oy * 6 + ox]);
                }
            }
        }
    }
    __syncthreads();
    float pbv = pb[ch];
#pragma unroll
    for (int s = 0; s < 36; ++s) smem[ch * 36 + s] = acc[s] + pbv;
    __syncthreads();

    const int b = b0 + bl;
    for (int n = ch; n < 1152; n += 256) {
        int cc = n / 36, s = n - cc * 36;
        float p8[8];
        float sn = 0.f;
#pragma unroll
        for (int d = 0; d < 8; ++d) {
            p8[d] = smem[(d * 32 + cc) * 36 + s];
            sn += p8[d] * p8[d];
        }
        float fac = sqrtf(sn) / (1.0f + sn);   // sn/(1+sn) * x/sqrt(sn)
        float4 o0, o1;
        o0.x = fac * p8[0]; o0.y = fac * p8[1]; o0.z = fac * p8[2]; o0.w = fac * p8[3];
        o1.x = fac * p8[4]; o1.y = fac * p8[5]; o1.z = fac * p8[6]; o1.w = fac * p8[7];
        float* up = u + ((size_t)b * 1152 + n) * 8;
        *(float4*)up = o0;
        *(float4*)(up + 4) = o1;
    }
}

// ---------------------------------------------------------------------------
// routing: one block per (b, c).  u_hat [1152][16] kept in LDS, 3 iterations,
// out[b][c][0..15] = v.
// ---------------------------------------------------------------------------
__global__ __launch_bounds__(256) void routing_kernel(
    const float* __restrict__ u,   // [B][1152][8]
    const float* __restrict__ W,   // [10][1152][8][16]
    float* __restrict__ out)       // [B][10][16]
{
    const int b = blockIdx.x;
    const int c = blockIdx.y;
    const int tid = threadIdx.x;
    __shared__ float uh[1152][16];
    __shared__ float bij[1152];
    __shared__ float red[4 * 17];
    __shared__ float sred[17];
    __shared__ float mred[4];

    const float* __restrict__ Wc = W + (size_t)c * (1152 * 128);
    const float* __restrict__ ub = u + (size_t)b * (1152 * 8);

    for (int n = tid; n < 1152; n += 256) {
        const float4* up = (const float4*)(ub + n * 8);
        float4 u0 = up[0], u1 = up[1];
        float uu[8] = {u0.x, u0.y, u0.z, u0.w, u1.x, u1.y, u1.z, u1.w};
        float acc[16];
#pragma unroll
        for (int o = 0; o < 16; ++o) acc[o] = 0.f;
        const float* wn = Wc + n * 128;
#pragma unroll
        for (int i = 0; i < 8; ++i)
#pragma unroll
            for (int o = 0; o < 16; ++o)
                acc[o] = fmaf(uu[i], wn[i * 16 + o], acc[o]);
#pragma unroll
        for (int o = 0; o < 16; ++o) uh[n][o] = acc[o];
        bij[n] = 0.f;
    }
    __syncthreads();

    const int wid = tid >> 6, lane = tid & 63;
    float v[16];
    for (int it = 0; it < 3; ++it) {
        // --- softmax max over nodes ---
        float m = -3.4e38f;
        for (int n = tid; n < 1152; n += 256) m = fmaxf(m, bij[n]);
#pragma unroll
        for (int off = 32; off > 0; off >>= 1) m = fmaxf(m, __shfl_down(m, off));
        if (lane == 0) mred[wid] = m;
        __syncthreads();
        float M = fmaxf(fmaxf(mred[0], mred[1]), fmaxf(mred[2], mred[3]));
        // --- sum exp and s_j partials in one pass ---
        float se = 0.f;
        float sp[16];
#pragma unroll
        for (int o = 0; o < 16; ++o) sp[o] = 0.f;
        for (int n = tid; n < 1152; n += 256) {
            float e = expf(bij[n] - M);
            se += e;
#pragma unroll
            for (int o = 0; o < 16; ++o) sp[o] = fmaf(e, uh[n][o], sp[o]);
        }
#pragma unroll
        for (int o = 0; o < 16; ++o)
#pragma unroll
            for (int off = 32; off > 0; off >>= 1) sp[o] += __shfl_down(sp[o], off);
#pragma unroll
        for (int off = 32; off > 0; off >>= 1) se += __shfl_down(se, off);
        if (lane == 0) {
#pragma unroll
            for (int o = 0; o < 16; ++o) red[wid * 17 + o] = sp[o];
            red[wid * 17 + 16] = se;
        }
        __syncthreads();
        if (tid < 17)
            sred[tid] = red[tid] + red[17 + tid] + red[34 + tid] + red[51 + tid];
        __syncthreads();
        // --- squash (computed redundantly by all threads) ---
        float inv = 1.0f / sred[16];
        float sn = 0.f;
        float sj[16];
#pragma unroll
        for (int o = 0; o < 16; ++o) { sj[o] = sred[o] * inv; sn = fmaf(sj[o], sj[o], sn); }
        float fac = sqrtf(sn) / (1.0f + sn);
#pragma unroll
        for (int o = 0; o < 16; ++o) v[o] = fac * sj[o];
        // --- agreement update ---
        if (it < 2) {
            for (int n = tid; n < 1152; n += 256) {
                float a = 0.f;
#pragma unroll
                for (int o = 0; o < 16; ++o) a = fmaf(uh[n][o], v[o], a);
                bij[n] += a;
            }
        }
        __syncthreads();
    }
    if (tid < 16) out[((size_t)b * 10 + c) * 16 + tid] = v[tid];
}

// ---------------------------------------------------------------------------
extern "C" void kernel_launch(void* const* d_in, const int* in_sizes, int n_in,
                              void* d_out, int out_size, void* d_ws, size_t ws_size,
                              hipStream_t stream) {
    const float* images  = (const float*)d_in[0];
    const float* conv1_w = (const float*)d_in[1];
    const float* conv1_b = (const float*)d_in[2];
    const float* prim_w  = (const float*)d_in[3];
    const float* prim_b  = (const float*)d_in[4];
    const float* W       = (const float*)d_in[5];
    float* out = (float*)d_out;

    const int B = in_sizes[0] / 784;

    float* ws = (float*)d_ws;
    const size_t NU  = (size_t)B * 1152 * 8;
    const size_t NT1 = 81 * 256;
    const size_t NT2 = (size_t)81 * 256 * 256;
    float* u   = ws;
    float* wT1 = ws + NU;
    float* wT2 = wT1 + NT1;
    float* xc  = wT2 + NT2;
    size_t fixedf = NU + NT1 + NT2;
    size_t availf = (ws_size / 4 > fixedf) ? ws_size / 4 - fixedf : 0;
    int Bc = (int)(availf / (400 * 256));
    if (Bc > B) Bc = B;
    if (Bc < 1) Bc = 1;

    prep_kernel<<<20736, 256, 0, stream>>>(conv1_w, prim_w, wT1, wT2);
    for (int b0 = 0; b0 < B; b0 += Bc) {
        int bc = (B - b0 < Bc) ? (B - b0) : Bc;
        conv1_kernel<<<bc, 256, 0, stream>>>(images, wT1, conv1_b, xc, b0);
        primary_kernel<<<bc, 256, 0, stream>>>(xc, wT2, prim_b, u, b0);
    }
    dim3 rg(B, 10);
    routing_kernel<<<rg, 256, 0, stream>>>(u, W, out);
}

// Round 2
// 1418.532 us; speedup vs baseline: 3.7806x; 3.7806x over previous
//
#include <hip/hip_runtime.h>
#include <hip/hip_bf16.h>
#include <cstddef>
#include <cstdint>

typedef __attribute__((ext_vector_type(8))) short v8s;     // 8 bf16 (4 VGPR)
typedef __attribute__((ext_vector_type(16))) float v16f;   // MFMA 32x32 acc

#define GLDS(SRC, DST) __builtin_amdgcn_global_load_lds( \
    (const __attribute__((address_space(1))) void*)(SRC), \
    (__attribute__((address_space(3))) void*)(DST), 16, 0, 0)

// RNE fp32 -> bf16 split: x ~= hi + lo, |x - hi - lo| <~ 2^-18 |x|
__device__ __forceinline__ void bf16split(float x, unsigned short& h, unsigned short& l) {
    union { float f; unsigned u; } a; a.f = x;
    unsigned r = a.u + 0x7fff + ((a.u >> 16) & 1);
    h = (unsigned short)(r >> 16);
    union { unsigned u; float f; } hb; hb.u = (unsigned)h << 16;
    union { float f; unsigned u; } b; b.f = x - hb.f;
    unsigned r2 = b.u + 0x7fff + ((b.u >> 16) & 1);
    l = (unsigned short)(r2 >> 16);
}

// ---------------------------------------------------------------------------
// prep: wT1[k*256+oc] = conv1_w[oc*81+k]  (fp32, for conv1)
//       wpk: primary weights, bf16 hi/lo split, pre-swizzled for LDS:
//       region (chunk,k): 256 rows (ch) x 256 B; row ch logical byte
//       v = half*128 + icl*2 stored at v ^ ((ch&15)<<4).
// grid 20736 x 256 == 4*81*256*64 threads.
// ---------------------------------------------------------------------------
__global__ __launch_bounds__(256) void prep_kernel(
    const float* __restrict__ cw, const float* __restrict__ pw,
    float* __restrict__ wT1, char* __restrict__ wpk)
{
    int idx = blockIdx.x * 256 + threadIdx.x;
    if (idx < 81 * 256) {
        int k = idx >> 8, oc = idx & 255;
        wT1[idx] = cw[oc * 81 + k];
    }
    int icl = idx & 63;
    int t = idx >> 6;
    int ch = t & 255; t >>= 8;          // t in [0, 324)
    int k = t % 81, chunk = t / 81;
    int ic = chunk * 64 + icl;
    float wv = pw[((ch << 8) + ic) * 81 + k];
    unsigned short h, l; bf16split(wv, h, l);
    size_t rowb = ((size_t)(chunk * 81 + k) * 256 + ch) * 256;
    int sw = (ch & 15) << 4;
    *(unsigned short*)(wpk + rowb + ((icl * 2) ^ sw)) = h;
    *(unsigned short*)(wpk + rowb + ((128 + icl * 2) ^ sw)) = l;
}

// ---------------------------------------------------------------------------
// conv1: [B,1,28,28] -> xc2 rows [bc*400] of 1024 B: [hi 256 bf16][lo 256 bf16]
// one block per image, thread = out channel
// ---------------------------------------------------------------------------
__global__ __launch_bounds__(256) void conv1_kernel(
    const float* __restrict__ img,   // [B][784]
    const float* __restrict__ wT1,   // [81][256]
    const float* __restrict__ bias,  // [256]
    char* __restrict__ xc2,          // [bc][400][1024 B]
    int b0)
{
    const int bl = blockIdx.x;
    const int oc = threadIdx.x;
    __shared__ float im[784];
    const float* ib = img + (size_t)(b0 + bl) * 784;
    for (int e = oc; e < 784; e += 256) im[e] = ib[e];
    float w[81];
#pragma unroll
    for (int k = 0; k < 81; ++k) w[k] = wT1[k * 256 + oc];
    float bv = bias[oc];
    __syncthreads();
    char* ob = xc2 + (size_t)bl * 409600;
    for (int oy = 0; oy < 20; ++oy) {
        for (int ox = 0; ox < 20; ++ox) {
            float a = bv;
#pragma unroll
            for (int ky = 0; ky < 9; ++ky)
#pragma unroll
                for (int kx = 0; kx < 9; ++kx)
                    a = fmaf(w[ky * 9 + kx], im[(oy + ky) * 28 + ox + kx], a);
            a = fmaxf(a, 0.f);
            unsigned short h, l; bf16split(a, h, l);
            char* rp = ob + (size_t)(oy * 20 + ox) * 1024;
            *(unsigned short*)(rp + oc * 2) = h;
            *(unsigned short*)(rp + 512 + oc * 2) = l;
        }
    }
}

// ---------------------------------------------------------------------------
// primary conv as implicit GEMM, split-bf16 (3 MFMA products), split-K over
// the 4 ic-chunks (blockIdx.y = g). C partials: part[g][M][256] fp32.
// Block: 256 thr = 4 waves, tile 64m x 256n, wave tile 64x64 (2x2 frags of
// 32x32x16). LDS: A 16 KB (gathered rows, src-side swizzle), B 64 KB
// (linear copy of pre-swizzled wpk).
// ---------------------------------------------------------------------------
__global__ __launch_bounds__(256, 2) void gemm_kernel(
    const char* __restrict__ xc2,   // [bc][400][1024 B]
    const char* __restrict__ wpk,   // [4][81][256][256 B] pre-swizzled
    float* __restrict__ part,       // [4][M][256]
    int bc)
{
    __shared__ __align__(128) char As[64 * 256];    // 16 KB
    __shared__ __align__(128) char Bs[256 * 256];   // 64 KB
    const int tid = threadIdx.x;
    const int w = tid >> 6, lane = tid & 63;
    const int m0 = blockIdx.x * 64;
    const int g = blockIdx.y;
    const int M = bc * 36;

    // Per-lane A-gather constants (4 issues of 1 KB per wave)
    int pbase[4]; int soff[4];
    for (int i = 0; i < 4; ++i) {
        int d = (w * 4 + i) * 1024 + lane * 16;
        int r = d >> 8;                      // LDS row = m - m0
        int v = (d & 255) ^ ((r & 15) << 4); // logical byte in 256-B row
        soff[i] = (v < 128) ? (g * 128 + v) : (512 + g * 128 + (v - 128));
        int m = m0 + r; if (m >= M) m = M - 1;
        int b = m / 36, s = m - b * 36;
        pbase[i] = b * 400 + (s / 6) * 40 + (s % 6) * 2;
    }

    v16f acc[2][2];
#pragma unroll
    for (int i = 0; i < 2; ++i)
#pragma unroll
        for (int j = 0; j < 2; ++j)
#pragma unroll
            for (int e = 0; e < 16; ++e) acc[i][j][e] = 0.f;

    const char* wg = wpk + (size_t)g * 81 * 65536;
    const int col = lane & 31, kg = lane >> 5;

    for (int k = 0; k < 81; ++k) {
        __syncthreads();                    // previous tile consumed
        const int koff = (k / 9) * 20 + (k % 9);
        // stage A (gathered rows, inverse-swizzled source)
#pragma unroll
        for (int i = 0; i < 4; ++i) {
            const char* src = xc2 + (size_t)(pbase[i] + koff) * 1024 + soff[i];
            GLDS(src, As + (w * 4 + i) * 1024);
        }
        // stage B (linear, pre-swizzled global)
        const char* bsrc = wg + (size_t)k * 65536 + w * 16384 + lane * 16;
#pragma unroll
        for (int i = 0; i < 16; ++i)
            GLDS(bsrc + i * 1024, Bs + w * 16384 + i * 1024);
        __syncthreads();                    // drains vmcnt

#pragma unroll
        for (int s = 0; s < 4; ++s) {
            const int vb = s * 32 + kg * 16;   // hi-plane byte base (16 B)
            v8s Ah[2], Al[2], Bh[2], Bl[2];
#pragma unroll
            for (int fm = 0; fm < 2; ++fm) {
                int r = fm * 32 + col;
                int sw = (r & 15) << 4;
                Ah[fm] = *(const v8s*)(As + r * 256 + (vb ^ sw));
                Al[fm] = *(const v8s*)(As + r * 256 + ((128 + vb) ^ sw));
            }
#pragma unroll
            for (int fn = 0; fn < 2; ++fn) {
                int ch = w * 64 + fn * 32 + col;
                int sw = (ch & 15) << 4;
                Bh[fn] = *(const v8s*)(Bs + ch * 256 + (vb ^ sw));
                Bl[fn] = *(const v8s*)(Bs + ch * 256 + ((128 + vb) ^ sw));
            }
#pragma unroll
            for (int fm = 0; fm < 2; ++fm)
#pragma unroll
                for (int fn = 0; fn < 2; ++fn) {
                    acc[fm][fn] = __builtin_amdgcn_mfma_f32_32x32x16_bf16(Al[fm], Bh[fn], acc[fm][fn], 0, 0, 0);
                    acc[fm][fn] = __builtin_amdgcn_mfma_f32_32x32x16_bf16(Ah[fm], Bl[fn], acc[fm][fn], 0, 0, 0);
                    acc[fm][fn] = __builtin_amdgcn_mfma_f32_32x32x16_bf16(Ah[fm], Bh[fn], acc[fm][fn], 0, 0, 0);
                }
        }
    }

    // store C partials: part[g][m][ch]
    float* pg = part + (size_t)g * M * 256;
    const bool full = (m0 + 64 <= M);
#pragma unroll
    for (int fm = 0; fm < 2; ++fm)
#pragma unroll
        for (int fn = 0; fn < 2; ++fn) {
            int ch = w * 64 + fn * 32 + col;
#pragma unroll
            for (int rg = 0; rg < 16; ++rg) {
                int row = (rg & 3) + 8 * (rg >> 2) + 4 * kg;
                int m = m0 + fm * 32 + row;
                if (full || m < M) pg[(size_t)m * 256 + ch] = acc[fm][fn][rg];
            }
        }
}

// ---------------------------------------------------------------------------
// partials -> +bias -> regroup -> squash -> u [B][1152][8]
// ---------------------------------------------------------------------------
__global__ __launch_bounds__(256) void prim2u_kernel(
    const float* __restrict__ part, const float* __restrict__ pb,
    float* __restrict__ u, int bc, int b0)
{
    int i = blockIdx.x * 256 + threadIdx.x;
    if (i >= bc * 1152) return;
    int bl = i / 1152, n = i - bl * 1152;
    int cc = n / 36, s = n - cc * 36;
    int m = bl * 36 + s;
    int M = bc * 36;
    float p8[8]; float sn = 0.f;
#pragma unroll
    for (int d = 0; d < 8; ++d) {
        int ch = d * 32 + cc;
        float v = pb[ch];
#pragma unroll
        for (int g = 0; g < 4; ++g) v += part[((size_t)g * M + m) * 256 + ch];
        p8[d] = v; sn += v * v;
    }
    float fac = sqrtf(sn) / (1.0f + sn);
    float4 o0, o1;
    o0.x = fac * p8[0]; o0.y = fac * p8[1]; o0.z = fac * p8[2]; o0.w = fac * p8[3];
    o1.x = fac * p8[4]; o1.y = fac * p8[5]; o1.z = fac * p8[6]; o1.w = fac * p8[7];
    float* up = u + ((size_t)(b0 + bl) * 1152 + n) * 8;
    *(float4*)up = o0;
    *(float4*)(up + 4) = o1;
}

// ---------------------------------------------------------------------------
// routing: one block per (b, c).  u_hat [1152][16] in LDS, 3 iterations.
// ---------------------------------------------------------------------------
__global__ __launch_bounds__(256) void routing_kernel(
    const float* __restrict__ u,   // [B][1152][8]
    const float* __restrict__ W,   // [10][1152][8][16]
    float* __restrict__ out)       // [B][10][16]
{
    const int b = blockIdx.x;
    const int c = blockIdx.y;
    const int tid = threadIdx.x;
    __shared__ float uh[1152][16];
    __shared__ float bij[1152];
    __shared__ float red[4 * 17];
    __shared__ float sred[17];
    __shared__ float mred[4];

    const float* __restrict__ Wc = W + (size_t)c * (1152 * 128);
    const float* __restrict__ ub = u + (size_t)b * (1152 * 8);

    for (int n = tid; n < 1152; n += 256) {
        const float4* up = (const float4*)(ub + n * 8);
        float4 u0 = up[0], u1 = up[1];
        float uu[8] = {u0.x, u0.y, u0.z, u0.w, u1.x, u1.y, u1.z, u1.w};
        float acc[16];
#pragma unroll
        for (int o = 0; o < 16; ++o) acc[o] = 0.f;
        const float* wn = Wc + n * 128;
#pragma unroll
        for (int i = 0; i < 8; ++i)
#pragma unroll
            for (int o = 0; o < 16; ++o)
                acc[o] = fmaf(uu[i], wn[i * 16 + o], acc[o]);
#pragma unroll
        for (int o = 0; o < 16; ++o) uh[n][o] = acc[o];
        bij[n] = 0.f;
    }
    __syncthreads();

    const int wid = tid >> 6, lane = tid & 63;
    float v[16];
    for (int it = 0; it < 3; ++it) {
        float m = -3.4e38f;
        for (int n = tid; n < 1152; n += 256) m = fmaxf(m, bij[n]);
#pragma unroll
        for (int off = 32; off > 0; off >>= 1) m = fmaxf(m, __shfl_down(m, off));
        if (lane == 0) mred[wid] = m;
        __syncthreads();
        float M = fmaxf(fmaxf(mred[0], mred[1]), fmaxf(mred[2], mred[3]));
        float se = 0.f;
        float sp[16];
#pragma unroll
        for (int o = 0; o < 16; ++o) sp[o] = 0.f;
        for (int n = tid; n < 1152; n += 256) {
            float e = expf(bij[n] - M);
            se += e;
#pragma unroll
            for (int o = 0; o < 16; ++o) sp[o] = fmaf(e, uh[n][o], sp[o]);
        }
#pragma unroll
        for (int o = 0; o < 16; ++o)
#pragma unroll
            for (int off = 32; off > 0; off >>= 1) sp[o] += __shfl_down(sp[o], off);
#pragma unroll
        for (int off = 32; off > 0; off >>= 1) se += __shfl_down(se, off);
        if (lane == 0) {
#pragma unroll
            for (int o = 0; o < 16; ++o) red[wid * 17 + o] = sp[o];
            red[wid * 17 + 16] = se;
        }
        __syncthreads();
        if (tid < 17)
            sred[tid] = red[tid] + red[17 + tid] + red[34 + tid] + red[51 + tid];
        __syncthreads();
        float inv = 1.0f / sred[16];
        float sn = 0.f;
        float sj[16];
#pragma unroll
        for (int o = 0; o < 16; ++o) { sj[o] = sred[o] * inv; sn = fmaf(sj[o], sj[o], sn); }
        float fac = sqrtf(sn) / (1.0f + sn);
#pragma unroll
        for (int o = 0; o < 16; ++o) v[o] = fac * sj[o];
        if (it < 2) {
            for (int n = tid; n < 1152; n += 256) {
                float a = 0.f;
#pragma unroll
                for (int o = 0; o < 16; ++o) a = fmaf(uh[n][o], v[o], a);
                bij[n] += a;
            }
        }
        __syncthreads();
    }
    if (tid < 16) out[((size_t)b * 10 + c) * 16 + tid] = v[tid];
}

// ---------------------------------------------------------------------------
extern "C" void kernel_launch(void* const* d_in, const int* in_sizes, int n_in,
                              void* d_out, int out_size, void* d_ws, size_t ws_size,
                              hipStream_t stream) {
    const float* images  = (const float*)d_in[0];
    const float* conv1_w = (const float*)d_in[1];
    const float* conv1_b = (const float*)d_in[2];
    const float* prim_w  = (const float*)d_in[3];
    const float* prim_b  = (const float*)d_in[4];
    const float* W       = (const float*)d_in[5];
    float* out = (float*)d_out;

    const int B = in_sizes[0] / 784;

    char* wsb = (char*)d_ws;
    float* u = (float*)wsb;
    size_t off = (size_t)B * 1152 * 8 * 4;
    float* wT1 = (float*)(wsb + off);
    off += 81 * 256 * 4;
    off = (off + 1023) & ~(size_t)1023;
    char* wpk = wsb + off;
    off += (size_t)4 * 81 * 256 * 256;          // 21.2 MB
    size_t rem = (ws_size > off) ? ws_size - off : 0;
    const size_t perimg = 409600 + 147456;       // xc2 + partials
    int Bc = (int)(rem / perimg);
    if (Bc > B) Bc = B;
    if (Bc < 1) Bc = 1;
    Bc &= ~15;                                    // multiple of 16 (exact tiles)
    if (Bc < 16) Bc = 1;

    prep_kernel<<<20736, 256, 0, stream>>>(conv1_w, prim_w, wT1, wpk);

    for (int b0 = 0; b0 < B; b0 += Bc) {
        int bc = (B - b0 < Bc) ? (B - b0) : Bc;
        char* xc2 = wsb + off;
        float* part = (float*)(xc2 + (size_t)Bc * 409600);
        conv1_kernel<<<bc, 256, 0, stream>>>(images, wT1, conv1_b, xc2, b0);
        dim3 gg((bc * 36 + 63) / 64, 4);
        gemm_kernel<<<gg, 256, 0, stream>>>(xc2, wpk, part, bc);
        int items = bc * 1152;
        prim2u_kernel<<<(items + 255) / 256, 256, 0, stream>>>(part, prim_b, u, bc, b0);
    }
    dim3 rg(B, 10);
    routing_kernel<<<rg, 256, 0, stream>>>(u, W, out);
}